// Round 2
// baseline (618.775 us; speedup 1.0000x reference)
//
#include <hip/hip_runtime.h>
#include <cstdint>
#include <cstddef>

typedef unsigned short u16;
typedef __attribute__((ext_vector_type(8))) __bf16 bf16x8;
typedef __attribute__((ext_vector_type(4))) float floatx4;

typedef const __attribute__((address_space(1))) void* gptr_t;
typedef __attribute__((address_space(3))) void* lptr_t;

__device__ __forceinline__ u16 f2b(float f) {
    unsigned u = __builtin_bit_cast(unsigned, f);
    u += 0x7fffu + ((u >> 16) & 1u);   // RNE; inputs are finite
    return (u16)(u >> 16);
}

// DPP row (16-lane) rotate-reductions — VALU pipe, no DS traffic.
template <int N>
__device__ __forceinline__ float ror_add(float x) {
    int y = __builtin_amdgcn_update_dpp(0, __builtin_bit_cast(int, x), 0x120 + N, 0xF, 0xF, true);
    return x + __builtin_bit_cast(float, y);
}
template <int N>
__device__ __forceinline__ float ror_max(float x) {
    int y = __builtin_amdgcn_update_dpp(0, __builtin_bit_cast(int, x), 0x120 + N, 0xF, 0xF, true);
    return fmaxf(x, __builtin_bit_cast(float, y));
}

// ---------------- fp32 -> bf16 casts ----------------
__global__ void cast_x(const float* __restrict__ in, u16* __restrict__ out, int n4) {
    const int stride = gridDim.x * blockDim.x;
    for (int i = blockIdx.x * blockDim.x + threadIdx.x; i < n4; i += stride) {
        const float4 v = ((const float4*)in)[i];
        ushort4 o;
        o.x = f2b(v.x); o.y = f2b(v.y); o.z = f2b(v.z); o.w = f2b(v.w);
        ((ushort4*)out)[i] = o;
    }
}

__global__ void cast_w(const float* __restrict__ Wq, const float* __restrict__ Wk,
                       const float* __restrict__ Wv, const float* __restrict__ Wo,
                       u16* __restrict__ Wqkv, u16* __restrict__ Wob) {
    const int stride = gridDim.x * blockDim.x;
    for (int i = blockIdx.x * blockDim.x + threadIdx.x; i < 1048576; i += stride) {
        const int which = i >> 18;          // 262144 float4 per matrix
        const int local = i & 0x3FFFF;
        const float* src = which == 0 ? Wq : which == 1 ? Wk : which == 2 ? Wv : Wo;
        const float4 v = ((const float4*)src)[local];
        ushort4 o;
        o.x = f2b(v.x); o.y = f2b(v.y); o.z = f2b(v.z); o.w = f2b(v.w);
        ushort4* dst = which < 3 ? (ushort4*)Wqkv + which * 262144 + local
                                 : (ushort4*)Wob + local;
        *dst = o;
    }
}

// ---------------- 256x256xBK64 pipelined 8-phase bf16 GEMM, C = A @ B^T + bias ----
// K fixed 1024 (16 K-tiles, 8 iterations x 2 tiles). 8 waves (2m x 4n).
// READ-AHEAD schedule: ds_reads issued in phase k feed the MFMAs of phase k+1,
// so LDS drain overlaps the MFMA cluster (compiler emits counted lgkmcnt, not 0).
//
// Read windows (4 or 8 ds_read_b128 per wave, balanced):
//  pre: aE<-buf0.A-lo, p0E<-buf0.B-lo      ph4: p1 <-buf1.B-hi (-> MFMA5)
//  ph0: p1 <-buf0.B-hi (-> MFMA1)          ph5: aO <-buf1.A-hi (-> MFMA6)
//  ph1: aO <-buf0.A-hi (-> MFMA2)          ph6: p0E<-buf0'.B-lo (-> next MFMA0/3)
//  ph2: p0O<-buf1.B-lo (-> MFMA4/7)        ph7: aE <-buf0'.A-lo (-> next MFMA0/1)
//  ph3: aE <-buf1.A-lo (-> MFMA4/5)
// MFMA_k: 0:aExp0E 1:aExp1 2:aOxp1 3:aOxp0E 4:aExp0O 5:aExp1 6:aOxp1 7:aOxp0O
//
// Stages (4 x global_load_lds, both halves of one matrix tile):
//  ph2: kt2.B->buf0.B   ph3: kt2.A->buf0.A   ph6: kt3.B->buf1.B   ph7: kt3.A->buf1.A
// Gates: uniform s_waitcnt vmcnt(4) at END of phases 1,2,5,6 (retire depth = 3
// phases, ~1000+ cy latency cover). WAR margins: every restage is >=2 phases +
// 1 barrier after the region's last read's consuming-MFMA lgkm. One barrier/phase.

#define MFMA16(va, vb, vc) __builtin_amdgcn_mfma_f32_16x16x32_bf16((va), (vb), (vc), 0, 0, 0)
#define PH_BAR()  __builtin_amdgcn_s_barrier()
#define SB0()     __builtin_amdgcn_sched_barrier(0)
#define VM4()     asm volatile("s_waitcnt vmcnt(4)" ::: "memory")
#define VM0()     asm volatile("s_waitcnt vmcnt(0)" ::: "memory")

#define MMA_BLK(af, bf, MI, TJ)                                                        \
    _Pragma("unroll")                                                                  \
    for (int i_ = 0; i_ < 4; ++i_) {                                                   \
        _Pragma("unroll")                                                              \
        for (int t_ = 0; t_ < 2; ++t_) {                                               \
            acc[(MI)+i_][(TJ)+t_] = MFMA16(af[i_][0], bf[t_][0], acc[(MI)+i_][(TJ)+t_]); \
            acc[(MI)+i_][(TJ)+t_] = MFMA16(af[i_][1], bf[t_][1], acc[(MI)+i_][(TJ)+t_]); \
        }                                                                              \
    }

template <bool OUT_BF16>
__global__ __launch_bounds__(512, 2)
void gemm8(const u16* __restrict__ A, const u16* __restrict__ B,
           const float* __restrict__ b0, const float* __restrict__ b1,
           const float* __restrict__ b2, void* __restrict__ Cout,
           int N, int mshift)
{
    __shared__ __align__(16) u16 lds[65536];   // 128 KiB: A[2buf][2half][8sub][512] | B same

    // XCD-aware bijective swizzle (nwg % 8 == 0 always here), m-major within n
    const int nwg = gridDim.x;
    const int bid = blockIdx.x;
    const int swz = (bid & 7) * (nwg >> 3) + (bid >> 3);
    const int ntile = swz >> mshift;
    const int mtile = swz & ((1 << mshift) - 1);
    const int bm0 = mtile << 8;
    const int bn0 = ntile << 8;

    const int tid  = threadIdx.x;
    const int lane = tid & 63;
    const int wv   = tid >> 6;      // 0..7
    const int wm   = wv >> 2;       // 0..1
    const int wn   = wv & 3;        // 0..3
    const int lrow = lane & 15;
    const int quad = lane >> 4;

    // staging: pre-swizzled global source, linear LDS dst (st_16x32 XOR)
    const int srow = lane >> 2;
    const int scol = ((lane & 3) * 8) ^ (((lane >> 5) & 1) << 4);
    const u16* aS = A + (size_t)(bm0 + wv * 16 + srow) * 1024 + scol;
    const u16* bS = B + (size_t)(bn0 + wv * 16 + srow) * 1024 + scol;
    u16* aD = lds +         wv * 1024 + lane * 8;
    u16* bD = lds + 32768 + wv * 1024 + lane * 8;

    // fragment read addressing (swizzled)
    const int laneSw = lrow * 32 + ((quad * 8) ^ ((lrow >> 3) << 4));
    const u16* pA = lds +         wm * 8192 + laneSw;   // +buf*16384 + i*1024 + kb*512
    const u16* pB = lds + 32768 + wn * 4096 + laneSw;   // +buf*16384 + t*1024 + kb*512

    auto stage2 = [&](const u16* src, u16* dst, int kt) {   // both halves: 4 loads
        #pragma unroll
        for (int h = 0; h < 2; ++h) {
            const u16* s = src + (size_t)h * 131072 + kt * 64;
            u16* d = dst + h * 8192;
            __builtin_amdgcn_global_load_lds((gptr_t)s,        (lptr_t)d,         16, 0, 0);
            __builtin_amdgcn_global_load_lds((gptr_t)(s + 32), (lptr_t)(d + 512), 16, 0, 0);
        }
    };

    bf16x8 aE[4][2], aO[4][2], p1[2][2], p0E[2][2], p0O[2][2];

    auto readA = [&](bf16x8 (&d)[4][2], int off) {
        #pragma unroll
        for (int i = 0; i < 4; ++i) {
            d[i][0] = *(const bf16x8*)(pA + off + i * 1024);
            d[i][1] = *(const bf16x8*)(pA + off + i * 1024 + 512);
        }
    };
    auto readB = [&](bf16x8 (&d)[2][2], int off) {
        #pragma unroll
        for (int t = 0; t < 2; ++t) {
            d[t][0] = *(const bf16x8*)(pB + off + t * 1024);
            d[t][1] = *(const bf16x8*)(pB + off + t * 1024 + 512);
        }
    };

    // ---- prologue: K0 + K1 fully staged; retire K0, keep K1 (8 loads) in flight
    stage2(bS, bD, 0);          // K0.B -> buf0.B
    stage2(aS, aD, 0);          // K0.A -> buf0.A
    asm volatile("" ::: "memory");
    stage2(bS, bD + 16384, 1);  // K1.B -> buf1.B
    stage2(aS, aD + 16384, 1);  // K1.A -> buf1.A
    asm volatile("s_waitcnt vmcnt(8)" ::: "memory");
    PH_BAR(); SB0();

    const floatx4 fz = {0.f, 0.f, 0.f, 0.f};
    floatx4 acc[8][4];
    #pragma unroll
    for (int i = 0; i < 8; ++i)
        #pragma unroll
        for (int t = 0; t < 4; ++t) acc[i][t] = fz;

    readA(aE, 0);       // buf0.A-lo  -> MFMA0/1
    readB(p0E, 0);      // buf0.B-lo  -> MFMA0/3

    for (int j = 0; j < 8; ++j) {
        const bool more = (j < 7);
        const int kt2 = 2 * j + 2;
        const int kt3 = 2 * j + 3;

        // ===== ph0: read p1<-buf0.B-hi; MFMA0 = aE x p0E
        readB(p1, 2048);
        SB0();
        __builtin_amdgcn_s_setprio(1);
        MMA_BLK(aE, p0E, 0, 0);
        __builtin_amdgcn_s_setprio(0);
        PH_BAR(); SB0();

        // ===== ph1: read aO<-buf0.A-hi; MFMA1 = aE x p1; gate vmcnt(4)
        readA(aO, 4096);
        SB0();
        __builtin_amdgcn_s_setprio(1);
        MMA_BLK(aE, p1, 0, 2);
        __builtin_amdgcn_s_setprio(0);
        VM4();
        PH_BAR(); SB0();

        // ===== ph2: stage kt2.B->buf0.B; read p0O<-buf1.B-lo; MFMA2 = aO x p1; gate
        if (more) stage2(bS, bD, kt2);
        readB(p0O, 16384);
        SB0();
        __builtin_amdgcn_s_setprio(1);
        MMA_BLK(aO, p1, 4, 2);
        __builtin_amdgcn_s_setprio(0);
        if (more) { VM4(); } else { VM0(); }
        PH_BAR(); SB0();

        // ===== ph3: stage kt2.A->buf0.A; read aE<-buf1.A-lo; MFMA3 = aO x p0E
        if (more) stage2(aS, aD, kt2);
        readA(aE, 16384);
        SB0();
        __builtin_amdgcn_s_setprio(1);
        MMA_BLK(aO, p0E, 4, 0);
        __builtin_amdgcn_s_setprio(0);
        PH_BAR(); SB0();

        // ===== ph4: read p1<-buf1.B-hi; MFMA4 = aE x p0O
        readB(p1, 16384 + 2048);
        SB0();
        __builtin_amdgcn_s_setprio(1);
        MMA_BLK(aE, p0O, 0, 0);
        __builtin_amdgcn_s_setprio(0);
        PH_BAR(); SB0();

        // ===== ph5: read aO<-buf1.A-hi; MFMA5 = aE x p1; gate vmcnt(4)
        readA(aO, 16384 + 4096);
        SB0();
        __builtin_amdgcn_s_setprio(1);
        MMA_BLK(aE, p1, 0, 2);
        __builtin_amdgcn_s_setprio(0);
        if (more) VM4();
        PH_BAR(); SB0();

        // ===== ph6: stage kt3.B->buf1.B; read p0E<-buf0.B-lo(new); MFMA6 = aO x p1; gate
        if (more) {
            stage2(bS, bD + 16384, kt3);
            readB(p0E, 0);
        }
        SB0();
        __builtin_amdgcn_s_setprio(1);
        MMA_BLK(aO, p1, 4, 2);
        __builtin_amdgcn_s_setprio(0);
        if (more) VM4();
        PH_BAR(); SB0();

        // ===== ph7: stage kt3.A->buf1.A; read aE<-buf0.A-lo(new); MFMA7 = aO x p0O
        if (more) {
            stage2(aS, aD + 16384, kt3);
            readA(aE, 0);
        }
        SB0();
        __builtin_amdgcn_s_setprio(1);
        MMA_BLK(aO, p0O, 4, 0);
        __builtin_amdgcn_s_setprio(0);
        PH_BAR(); SB0();
    }

    // ---- epilogue: bias + store ----
    float bsv[4];
    #pragma unroll
    for (int t = 0; t < 4; ++t) {
        const int n = bn0 + wn * 64 + t * 16 + lrow;
        const float* bp = n < 1024 ? b0 : (n < 2048 ? b1 : b2);
        bsv[t] = bp[n & 1023];
    }
    #pragma unroll
    for (int i = 0; i < 8; ++i) {
        const int mbase = bm0 + wm * 128 + i * 16 + quad * 4;
        #pragma unroll
        for (int t = 0; t < 4; ++t) {
            const int n = bn0 + wn * 64 + t * 16 + lrow;
            #pragma unroll
            for (int r = 0; r < 4; ++r) {
                const float v = acc[i][t][r] + bsv[t];
                const size_t idx = (size_t)(mbase + r) * N + n;
                if constexpr (OUT_BF16) ((u16*)Cout)[idx] = f2b(v);
                else                    ((float*)Cout)[idx] = v;
            }
        }
    }
}

// ---------------- attention v3: DPP softmax (unchanged) ----------------
__global__ __launch_bounds__(256)
void attn_v3(const u16* __restrict__ QKV, u16* __restrict__ Z)
{
    __shared__ __align__(16) u16 sV[4][1024];     // per-wave V^T, phys_row=(d&7)*8+(d>>3)
    __shared__ __align__(16) u16 sA[4][640];      // per-wave A, rows of 40 (k=16..31 zeroed)
    __shared__ __align__(16) u16 sY[16 * 1152];   // [t][h][72]

    const int tid  = threadIdx.x;
    const int lane = tid & 63;
    const int wv   = tid >> 6;
    const int lrow = lane & 15;
    const int quad = lane >> 4;
    const int pp   = lane >> 3;   // l-pair 0..7
    const int cc   = lane & 7;    // d-chunk 0..7

    #pragma unroll
    for (int i = 0; i < 4; i++) {
        const int idx = i * 64 + lane;
        sA[wv][(idx >> 4) * 40 + 16 + (idx & 15)] = 0;
    }

    const int tgrp = blockIdx.x * 16;
    const int nb   = tgrp >> 13;
    const int sg   = (tgrp & 8191) >> 4;

    const floatx4 fzero = {0.f, 0.f, 0.f, 0.f};

    for (int tt = 0; tt < 4; tt++) {
        const int t = wv * 4 + tt;
        const u16* base = QKV + (size_t)(tgrp + t) * 3072;

        const bf16x8 q0 = *(const bf16x8*)(base + lrow * 64      + quad * 8);
        const bf16x8 q1 = *(const bf16x8*)(base + lrow * 64 + 32 + quad * 8);
        const bf16x8 k0 = *(const bf16x8*)(base + 1024 + lrow * 64      + quad * 8);
        const bf16x8 k1 = *(const bf16x8*)(base + 1024 + lrow * 64 + 32 + quad * 8);

        const u16* V = base + 2048;
        const bf16x8 va = *(const bf16x8*)(V + (2 * pp)     * 64 + cc * 8);
        const bf16x8 vb = *(const bf16x8*)(V + (2 * pp + 1) * 64 + cc * 8);
        #pragma unroll
        for (int s = 0; s < 8; s++) {
            const unsigned pv = (unsigned)__builtin_bit_cast(u16, (__bf16)va[s]) |
                                ((unsigned)__builtin_bit_cast(u16, (__bf16)vb[s]) << 16);
            *(unsigned*)&sV[wv][(s * 8 + cc) * 16 + 2 * pp] = pv;
        }

        floatx4 e = fzero;
        e = __builtin_amdgcn_mfma_f32_16x16x32_bf16(q0, k0, e, 0, 0, 0);
        e = __builtin_amdgcn_mfma_f32_16x16x32_bf16(q1, k1, e, 0, 0, 0);

        #pragma unroll
        for (int r = 0; r < 4; r++) {
            const float xv = e[r] * 0.03125f;    // 1/sqrt(1024)
            float mx = xv;
            mx = ror_max<1>(mx); mx = ror_max<2>(mx);
            mx = ror_max<4>(mx); mx = ror_max<8>(mx);
            const float p = __expf(xv - mx);
            float s = p;
            s = ror_add<1>(s); s = ror_add<2>(s);
            s = ror_add<4>(s); s = ror_add<8>(s);
            sA[wv][(quad * 4 + r) * 40 + lrow] = f2b(p * __builtin_amdgcn_rcpf(s));
        }

        const bf16x8 af = *(const bf16x8*)&sA[wv][lrow * 40 + quad * 8];

        bf16x8 bfr[4];
        #pragma unroll
        for (int j = 0; j < 4; j++)
            #pragma unroll
            for (int jj = 0; jj < 8; jj++)
                bfr[j][jj] = __builtin_bit_cast(__bf16, (u16)0);
        if (quad < 2) {
            #pragma unroll
            for (int j = 0; j < 4; j++) {
                const int pr = (lrow & 7) * 8 + j * 2 + (lrow >> 3);
                bfr[j] = *(const bf16x8*)&sV[wv][pr * 16 + quad * 8];
            }
        }

        #pragma unroll
        for (int j = 0; j < 4; j++) {
            const floatx4 y = __builtin_amdgcn_mfma_f32_16x16x32_bf16(af, bfr[j], fzero, 0, 0, 0);
            #pragma unroll
            for (int r = 0; r < 4; r++)
                sY[t * 1152 + (quad * 4 + r) * 72 + j * 16 + lrow] = f2b(y[r]);
        }
    }

    __syncthreads();

    const int h   = tid >> 4;
    const int pos = tid & 15;
    u16* zrow = Z + (size_t)(nb * 8192 + h * 512 + sg) * 1024;
    #pragma unroll
    for (int it = 0; it < 8; it++) {
        const int c16 = it * 16 + pos;
        const int t = c16 >> 3, dc = c16 & 7;
        const uint4 v = *(const uint4*)&sY[t * 1152 + h * 72 + dc * 8];
        *(uint4*)(zrow + c16 * 8) = v;
    }
}

// ---------------- launch ----------------
extern "C" void kernel_launch(void* const* d_in, const int* in_sizes, int n_in,
                              void* d_out, int out_size, void* d_ws, size_t ws_size,
                              hipStream_t stream)
{
    (void)in_sizes; (void)n_in; (void)out_size;
    const float* x  = (const float*)d_in[0];
    const float* Wq = (const float*)d_in[1];
    const float* Wk = (const float*)d_in[2];
    const float* Wv = (const float*)d_in[3];
    const float* Wo = (const float*)d_in[4];
    const float* bq = (const float*)d_in[5];
    const float* bk = (const float*)d_in[6];
    const float* bv = (const float*)d_in[7];
    const float* bo = (const float*)d_in[8];

    const size_t Mtot = 32768;   // 4 * 8192 tokens
    char* ws = (char*)d_ws;
    u16* Xbf  = (u16*)ws;                                   // 64 MB
    u16* Wqkv = (u16*)(ws + (64ull << 20));                 // 6 MB
    u16* Wob  = (u16*)(ws + (64ull << 20) + (6ull << 20));  // 2 MB
    char* dyn = ws + (72ull << 20);
    const size_t fixed = (72ull << 20);

    int c = 4;
    for (int cc = 1; cc <= 4; cc <<= 1) {
        size_t Rr = Mtot / cc;
        if (fixed + Rr * 3072 * 2 + Rr * 1024 * 2 <= ws_size) { c = cc; break; }
    }
    const size_t R = Mtot / c;
    u16* QKV = (u16*)dyn;
    u16* Zb  = (u16*)(dyn + R * 3072 * 2);

    cast_x<<<dim3(4096), dim3(256), 0, stream>>>(x, Xbf, (int)(Mtot * 1024 / 4));
    cast_w<<<dim3(1024), dim3(256), 0, stream>>>(Wq, Wk, Wv, Wo, Wqkv, Wob);

    const int mt  = (int)(R >> 8);          // 256-row tiles; power of 2
    const int msh = __builtin_ctz((unsigned)mt);

    for (int ci = 0; ci < c; ci++) {
        const u16* Ab   = Xbf + (size_t)ci * R * 1024;
        float*     outp = (float*)d_out + (size_t)ci * R * 1024;
        gemm8<true><<<dim3(mt * 12), dim3(512), 0, stream>>>(Ab, Wqkv, bq, bk, bv, QKV, 3072, msh);
        attn_v3<<<dim3((unsigned)(R / 16)), dim3(256), 0, stream>>>(QKV, Zb);
        gemm8<false><<<dim3(mt * 4), dim3(512), 0, stream>>>(Zb, Wob, bo, bo, bo, outp, 1024, msh);
    }
}

// Round 3
// 572.513 us; speedup vs baseline: 1.0808x; 1.0808x over previous
//
#include <hip/hip_runtime.h>
#include <cstdint>
#include <cstddef>

typedef unsigned short u16;
typedef __attribute__((ext_vector_type(8))) __bf16 bf16x8;
typedef __attribute__((ext_vector_type(4))) float floatx4;

typedef const __attribute__((address_space(1))) void* gptr_t;
typedef __attribute__((address_space(3))) void* lptr_t;

__device__ __forceinline__ u16 f2b(float f) {
    unsigned u = __builtin_bit_cast(unsigned, f);
    u += 0x7fffu + ((u >> 16) & 1u);   // RNE; inputs are finite
    return (u16)(u >> 16);
}

// DPP row (16-lane) rotate-reductions — VALU pipe, no DS traffic.
template <int N>
__device__ __forceinline__ float ror_add(float x) {
    int y = __builtin_amdgcn_update_dpp(0, __builtin_bit_cast(int, x), 0x120 + N, 0xF, 0xF, true);
    return x + __builtin_bit_cast(float, y);
}
template <int N>
__device__ __forceinline__ float ror_max(float x) {
    int y = __builtin_amdgcn_update_dpp(0, __builtin_bit_cast(int, x), 0x120 + N, 0xF, 0xF, true);
    return fmaxf(x, __builtin_bit_cast(float, y));
}

// ---------------- fp32 -> bf16 casts ----------------
__global__ void cast_x(const float* __restrict__ in, u16* __restrict__ out, int n4) {
    const int stride = gridDim.x * blockDim.x;
    for (int i = blockIdx.x * blockDim.x + threadIdx.x; i < n4; i += stride) {
        const float4 v = ((const float4*)in)[i];
        ushort4 o;
        o.x = f2b(v.x); o.y = f2b(v.y); o.z = f2b(v.z); o.w = f2b(v.w);
        ((ushort4*)out)[i] = o;
    }
}

__global__ void cast_w(const float* __restrict__ Wq, const float* __restrict__ Wk,
                       const float* __restrict__ Wv, const float* __restrict__ Wo,
                       u16* __restrict__ Wqkv, u16* __restrict__ Wob) {
    const int stride = gridDim.x * blockDim.x;
    for (int i = blockIdx.x * blockDim.x + threadIdx.x; i < 1048576; i += stride) {
        const int which = i >> 18;          // 262144 float4 per matrix
        const int local = i & 0x3FFFF;
        const float* src = which == 0 ? Wq : which == 1 ? Wk : which == 2 ? Wv : Wo;
        const float4 v = ((const float4*)src)[local];
        ushort4 o;
        o.x = f2b(v.x); o.y = f2b(v.y); o.z = f2b(v.z); o.w = f2b(v.w);
        ushort4* dst = which < 3 ? (ushort4*)Wqkv + which * 262144 + local
                                 : (ushort4*)Wob + local;
        *dst = o;
    }
}

// ---------------- 256x256xBK64 8-phase bf16 GEMM, C = A @ B^T + bias ----------------
// (Round-1 verified structure: 215 us, MfmaUtil 42%, zero bank conflicts, no spill.
//  Round-2's read-ahead variant spilled (+70MB scratch writes) — reverted.)
// K fixed at 1024 (16 K-tiles -> 8 iterations of 2 tiles).
// 8 waves (2m x 4n), per-wave 128x64 output = acc[8][4] 16x16 fragments.
// LDS 128 KiB: st_16x32 XOR swizzle on BOTH pre-swizzled global source (gload_lds
// writes linearly) and the ds_read address.
// Per phase: {ds_reads, stage 1 half-tile (2 x gload_lds), barrier, lgkmcnt(0),
// setprio(1), 16 MFMA, setprio(0), barrier}; counted vmcnt(4) at phases 3 and 7.

#define MFMA16(va, vb, vc) __builtin_amdgcn_mfma_f32_16x16x32_bf16((va), (vb), (vc), 0, 0, 0)
#define PH_BAR()  __builtin_amdgcn_s_barrier()
#define PH_LGKM() asm volatile("s_waitcnt lgkmcnt(0)" ::: "memory")

template <bool OUT_BF16>
__global__ __launch_bounds__(512, 2)
void gemm8(const u16* __restrict__ A, const u16* __restrict__ B,
           const float* __restrict__ b0, const float* __restrict__ b1,
           const float* __restrict__ b2, void* __restrict__ Cout,
           int N, int mshift)
{
    __shared__ __align__(16) u16 lds[65536];   // 128 KiB

    // XCD-aware bijective swizzle (nwg % 8 == 0 always here), m-major within n
    const int nwg = gridDim.x;
    const int bid = blockIdx.x;
    const int swz = (bid & 7) * (nwg >> 3) + (bid >> 3);
    const int ntile = swz >> mshift;
    const int mtile = swz & ((1 << mshift) - 1);
    const int bm0 = mtile << 8;
    const int bn0 = ntile << 8;

    const int tid  = threadIdx.x;
    const int lane = tid & 63;
    const int wv   = tid >> 6;      // 0..7
    const int wm   = wv >> 2;       // 0..1
    const int wn   = wv & 3;        // 0..3
    const int lrow = lane & 15;
    const int quad = lane >> 4;

    // ---- staging addressing (pre-swizzled global source, linear LDS dst) ----
    const int srow = lane >> 2;                                   // 0..15 within subtile
    const int scol = ((lane & 3) * 8) ^ (((lane >> 5) & 1) << 4); // inverse == forward XOR
    const u16* aS = A + (size_t)(bm0 + wv * 16 + srow) * 1024 + scol;
    const u16* bS = B + (size_t)(bn0 + wv * 16 + srow) * 1024 + scol;
    u16* aD = lds +         wv * 1024 + lane * 8;   // + buf*16384 + half*8192 (+512 for kb=1)
    u16* bD = lds + 32768 + wv * 1024 + lane * 8;

    // ---- fragment read addressing (swizzled) ----
    const int laneSw = lrow * 32 + ((quad * 8) ^ ((lrow >> 3) << 4));
    const u16* pA = lds +         wm * 8192 + laneSw;   // + buf*16384 + i*1024 + kb*512
    const u16* pB = lds + 32768 + wn * 4096 + laneSw;   // + buf*16384 + t*1024 + kb*512

    auto stage = [&](const u16* src, u16* dst, int kt, int half, int buf) {
        const u16* s = src + (size_t)half * 131072 + kt * 64;
        u16* d = dst + buf * 16384 + half * 8192;
        __builtin_amdgcn_global_load_lds((gptr_t)s,        (lptr_t)d,         16, 0, 0);
        __builtin_amdgcn_global_load_lds((gptr_t)(s + 32), (lptr_t)(d + 512), 16, 0, 0);
    };

    // ---- prologue: K0 fully (buf0) + K1.B halves (buf1); retire K0, keep K1.B in flight
    stage(aS, aD, 0, 0, 0);
    stage(aS, aD, 0, 1, 0);
    stage(bS, bD, 0, 0, 0);
    stage(bS, bD, 0, 1, 0);
    asm volatile("" ::: "memory");      // pin issue order: K0 group before K1 group
    stage(bS, bD, 1, 0, 1);
    stage(bS, bD, 1, 1, 1);
    asm volatile("s_waitcnt vmcnt(4)" ::: "memory");
    PH_BAR();

    const floatx4 fz = {0.f, 0.f, 0.f, 0.f};
    floatx4 acc[8][4];
    #pragma unroll
    for (int i = 0; i < 8; ++i)
        #pragma unroll
        for (int t = 0; t < 4; ++t) acc[i][t] = fz;

    bf16x8 a[4][2], p0[2][2], p1[2][2];

    for (int j = 0; j < 8; ++j) {
        const int kt1 = 2 * j + 1;
        const int kt2 = 2 * j + 2;
        const int kt3 = 2 * j + 3;
        const bool more = (j < 7);

        // ===== phase 0: buf0 reads A(m0-3)+B(n0-1) [12]; mfma acc[0-3][0-1]
        #pragma unroll
        for (int i = 0; i < 4; ++i) {
            a[i][0] = *(const bf16x8*)(pA + i * 1024);
            a[i][1] = *(const bf16x8*)(pA + i * 1024 + 512);
        }
        #pragma unroll
        for (int t = 0; t < 2; ++t) {
            p0[t][0] = *(const bf16x8*)(pB + t * 1024);
            p0[t][1] = *(const bf16x8*)(pB + t * 1024 + 512);
        }
        stage(aS, aD, kt1, 0, 1);
        PH_BAR(); PH_LGKM();
        __builtin_amdgcn_s_setprio(1);
        #pragma unroll
        for (int i = 0; i < 4; ++i)
            #pragma unroll
            for (int t = 0; t < 2; ++t) {
                acc[i][t] = MFMA16(a[i][0], p0[t][0], acc[i][t]);
                acc[i][t] = MFMA16(a[i][1], p0[t][1], acc[i][t]);
            }
        __builtin_amdgcn_s_setprio(0);
        PH_BAR();

        // ===== phase 1: buf0 reads B(n2-3) [4]; mfma acc[0-3][2-3]
        #pragma unroll
        for (int t = 0; t < 2; ++t) {
            p1[t][0] = *(const bf16x8*)(pB + 2048 + t * 1024);
            p1[t][1] = *(const bf16x8*)(pB + 2048 + t * 1024 + 512);
        }
        stage(aS, aD, kt1, 1, 1);
        PH_BAR(); PH_LGKM();
        __builtin_amdgcn_s_setprio(1);
        #pragma unroll
        for (int i = 0; i < 4; ++i)
            #pragma unroll
            for (int t = 0; t < 2; ++t) {
                acc[i][2 + t] = MFMA16(a[i][0], p1[t][0], acc[i][2 + t]);
                acc[i][2 + t] = MFMA16(a[i][1], p1[t][1], acc[i][2 + t]);
            }
        __builtin_amdgcn_s_setprio(0);
        PH_BAR();

        // ===== phase 2: buf0 reads A(m4-7) [8]; mfma acc[4-7][2-3]
        #pragma unroll
        for (int i = 0; i < 4; ++i) {
            a[i][0] = *(const bf16x8*)(pA + 4096 + i * 1024);
            a[i][1] = *(const bf16x8*)(pA + 4096 + i * 1024 + 512);
        }
        if (more) stage(bS, bD, kt2, 0, 0);
        PH_BAR(); PH_LGKM();
        __builtin_amdgcn_s_setprio(1);
        #pragma unroll
        for (int i = 0; i < 4; ++i)
            #pragma unroll
            for (int t = 0; t < 2; ++t) {
                acc[4 + i][2 + t] = MFMA16(a[i][0], p1[t][0], acc[4 + i][2 + t]);
                acc[4 + i][2 + t] = MFMA16(a[i][1], p1[t][1], acc[4 + i][2 + t]);
            }
        __builtin_amdgcn_s_setprio(0);
        PH_BAR();

        // ===== phase 3: no reads; mfma acc[4-7][0-1]; counted vmcnt protects phase-4 reads
        if (more) stage(bS, bD, kt2, 1, 0);
        PH_BAR();
        __builtin_amdgcn_s_setprio(1);
        #pragma unroll
        for (int i = 0; i < 4; ++i)
            #pragma unroll
            for (int t = 0; t < 2; ++t) {
                acc[4 + i][t] = MFMA16(a[i][0], p0[t][0], acc[4 + i][t]);
                acc[4 + i][t] = MFMA16(a[i][1], p0[t][1], acc[4 + i][t]);
            }
        __builtin_amdgcn_s_setprio(0);
        if (more) asm volatile("s_waitcnt vmcnt(4)" ::: "memory");
        else      asm volatile("s_waitcnt vmcnt(0)" ::: "memory");
        PH_BAR();

        // ===== phase 4: buf1 reads A(m0-3)+B(n0-1); mfma acc[0-3][0-1]
        #pragma unroll
        for (int i = 0; i < 4; ++i) {
            a[i][0] = *(const bf16x8*)(pA + 16384 + i * 1024);
            a[i][1] = *(const bf16x8*)(pA + 16384 + i * 1024 + 512);
        }
        #pragma unroll
        for (int t = 0; t < 2; ++t) {
            p0[t][0] = *(const bf16x8*)(pB + 16384 + t * 1024);
            p0[t][1] = *(const bf16x8*)(pB + 16384 + t * 1024 + 512);
        }
        if (more) stage(aS, aD, kt2, 0, 0);
        PH_BAR(); PH_LGKM();
        __builtin_amdgcn_s_setprio(1);
        #pragma unroll
        for (int i = 0; i < 4; ++i)
            #pragma unroll
            for (int t = 0; t < 2; ++t) {
                acc[i][t] = MFMA16(a[i][0], p0[t][0], acc[i][t]);
                acc[i][t] = MFMA16(a[i][1], p0[t][1], acc[i][t]);
            }
        __builtin_amdgcn_s_setprio(0);
        PH_BAR();

        // ===== phase 5: buf1 reads B(n2-3); mfma acc[0-3][2-3]
        #pragma unroll
        for (int t = 0; t < 2; ++t) {
            p1[t][0] = *(const bf16x8*)(pB + 16384 + 2048 + t * 1024);
            p1[t][1] = *(const bf16x8*)(pB + 16384 + 2048 + t * 1024 + 512);
        }
        if (more) stage(aS, aD, kt2, 1, 0);
        PH_BAR(); PH_LGKM();
        __builtin_amdgcn_s_setprio(1);
        #pragma unroll
        for (int i = 0; i < 4; ++i)
            #pragma unroll
            for (int t = 0; t < 2; ++t) {
                acc[i][2 + t] = MFMA16(a[i][0], p1[t][0], acc[i][2 + t]);
                acc[i][2 + t] = MFMA16(a[i][1], p1[t][1], acc[i][2 + t]);
            }
        __builtin_amdgcn_s_setprio(0);
        PH_BAR();

        // ===== phase 6: buf1 reads A(m4-7); mfma acc[4-7][2-3]
        #pragma unroll
        for (int i = 0; i < 4; ++i) {
            a[i][0] = *(const bf16x8*)(pA + 16384 + 4096 + i * 1024);
            a[i][1] = *(const bf16x8*)(pA + 16384 + 4096 + i * 1024 + 512);
        }
        if (more) stage(bS, bD, kt3, 0, 1);
        PH_BAR(); PH_LGKM();
        __builtin_amdgcn_s_setprio(1);
        #pragma unroll
        for (int i = 0; i < 4; ++i)
            #pragma unroll
            for (int t = 0; t < 2; ++t) {
                acc[4 + i][2 + t] = MFMA16(a[i][0], p1[t][0], acc[4 + i][2 + t]);
                acc[4 + i][2 + t] = MFMA16(a[i][1], p1[t][1], acc[4 + i][2 + t]);
            }
        __builtin_amdgcn_s_setprio(0);
        PH_BAR();

        // ===== phase 7: no reads; mfma acc[4-7][0-1]; counted vmcnt protects next ph0
        if (more) stage(bS, bD, kt3, 1, 1);
        PH_BAR();
        __builtin_amdgcn_s_setprio(1);
        #pragma unroll
        for (int i = 0; i < 4; ++i)
            #pragma unroll
            for (int t = 0; t < 2; ++t) {
                acc[4 + i][t] = MFMA16(a[i][0], p0[t][0], acc[4 + i][t]);
                acc[4 + i][t] = MFMA16(a[i][1], p0[t][1], acc[4 + i][t]);
            }
        __builtin_amdgcn_s_setprio(0);
        asm volatile("s_waitcnt vmcnt(4)" ::: "memory");
        PH_BAR();
    }

    // ---- epilogue: bias + store ----
    float bsv[4];
    #pragma unroll
    for (int t = 0; t < 4; ++t) {
        const int n = bn0 + wn * 64 + t * 16 + lrow;
        const float* bp = n < 1024 ? b0 : (n < 2048 ? b1 : b2);
        bsv[t] = bp[n & 1023];
    }
    #pragma unroll
    for (int i = 0; i < 8; ++i) {
        const int mbase = bm0 + wm * 128 + i * 16 + quad * 4;
        #pragma unroll
        for (int t = 0; t < 4; ++t) {
            const int n = bn0 + wn * 64 + t * 16 + lrow;
            #pragma unroll
            for (int r = 0; r < 4; ++r) {
                const float v = acc[i][t][r] + bsv[t];
                const size_t idx = (size_t)(mbase + r) * N + n;
                if constexpr (OUT_BF16) ((u16*)Cout)[idx] = f2b(v);
                else                    ((float*)Cout)[idx] = v;
            }
        }
    }
}

// ---------------- attention v4: DPP softmax + pipelined token loop ----------------
// Change vs v3: software-pipeline the 4-token loop — issue token tt+1's six global
// loads (Q,K,V fragments) before processing token tt, so ~900cy HBM latency hides
// under MFMA/softmax/LDS work. Named registers + explicit swap (no runtime-indexed
// arrays -> no scratch). Math identical to v3.
__global__ __launch_bounds__(256)
void attn_v3(const u16* __restrict__ QKV, u16* __restrict__ Z)
{
    __shared__ __align__(16) u16 sV[4][1024];     // per-wave V^T, phys_row=(d&7)*8+(d>>3)
    __shared__ __align__(16) u16 sA[4][640];      // per-wave A, rows of 40 (k=16..31 zeroed)
    __shared__ __align__(16) u16 sY[16 * 1152];   // [t][h][72]

    const int tid  = threadIdx.x;
    const int lane = tid & 63;
    const int wv   = tid >> 6;
    const int lrow = lane & 15;
    const int quad = lane >> 4;
    const int pp   = lane >> 3;   // l-pair 0..7
    const int cc   = lane & 7;    // d-chunk 0..7

    #pragma unroll
    for (int i = 0; i < 4; i++) {
        const int idx = i * 64 + lane;
        sA[wv][(idx >> 4) * 40 + 16 + (idx & 15)] = 0;
    }

    const int tgrp = blockIdx.x * 16;
    const int nb   = tgrp >> 13;
    const int sg   = (tgrp & 8191) >> 4;

    const floatx4 fzero = {0.f, 0.f, 0.f, 0.f};

    const u16* base = QKV + (size_t)(tgrp + wv * 4) * 3072;

    // preload token 0
    bf16x8 cq0 = *(const bf16x8*)(base + lrow * 64      + quad * 8);
    bf16x8 cq1 = *(const bf16x8*)(base + lrow * 64 + 32 + quad * 8);
    bf16x8 ck0 = *(const bf16x8*)(base + 1024 + lrow * 64      + quad * 8);
    bf16x8 ck1 = *(const bf16x8*)(base + 1024 + lrow * 64 + 32 + quad * 8);
    bf16x8 cva = *(const bf16x8*)(base + 2048 + (2 * pp)     * 64 + cc * 8);
    bf16x8 cvb = *(const bf16x8*)(base + 2048 + (2 * pp + 1) * 64 + cc * 8);

    #pragma unroll
    for (int tt = 0; tt < 4; tt++) {
        const int t = wv * 4 + tt;

        // prefetch token tt+1 (in flight across this token's compute)
        bf16x8 nq0, nq1, nk0, nk1, nva, nvb;
        if (tt < 3) {
            const u16* nbase = base + 3072;
            nq0 = *(const bf16x8*)(nbase + lrow * 64      + quad * 8);
            nq1 = *(const bf16x8*)(nbase + lrow * 64 + 32 + quad * 8);
            nk0 = *(const bf16x8*)(nbase + 1024 + lrow * 64      + quad * 8);
            nk1 = *(const bf16x8*)(nbase + 1024 + lrow * 64 + 32 + quad * 8);
            nva = *(const bf16x8*)(nbase + 2048 + (2 * pp)     * 64 + cc * 8);
            nvb = *(const bf16x8*)(nbase + 2048 + (2 * pp + 1) * 64 + cc * 8);
        }

        // V load + transpose into per-wave LDS (conflict-free b32 writes)
        #pragma unroll
        for (int s = 0; s < 8; s++) {
            const unsigned pv = (unsigned)__builtin_bit_cast(u16, (__bf16)cva[s]) |
                                ((unsigned)__builtin_bit_cast(u16, (__bf16)cvb[s]) << 16);
            *(unsigned*)&sV[wv][(s * 8 + cc) * 16 + 2 * pp] = pv;
        }

        floatx4 e = fzero;
        e = __builtin_amdgcn_mfma_f32_16x16x32_bf16(cq0, ck0, e, 0, 0, 0);
        e = __builtin_amdgcn_mfma_f32_16x16x32_bf16(cq1, ck1, e, 0, 0, 0);

        // softmax over l (= the 16 lanes of this quad's DPP row), pure VALU
        #pragma unroll
        for (int r = 0; r < 4; r++) {
            const float xv = e[r] * 0.03125f;    // 1/sqrt(1024)
            float mx = xv;
            mx = ror_max<1>(mx); mx = ror_max<2>(mx);
            mx = ror_max<4>(mx); mx = ror_max<8>(mx);
            const float p = __expf(xv - mx);
            float s = p;
            s = ror_add<1>(s); s = ror_add<2>(s);
            s = ror_add<4>(s); s = ror_add<8>(s);
            sA[wv][(quad * 4 + r) * 40 + lrow] = f2b(p * __builtin_amdgcn_rcpf(s));
        }

        const bf16x8 af = *(const bf16x8*)&sA[wv][lrow * 40 + quad * 8];

        bf16x8 bfr[4];
        #pragma unroll
        for (int j = 0; j < 4; j++)
            #pragma unroll
            for (int jj = 0; jj < 8; jj++)
                bfr[j][jj] = __builtin_bit_cast(__bf16, (u16)0);
        if (quad < 2) {
            #pragma unroll
            for (int j = 0; j < 4; j++) {
                const int pr = (lrow & 7) * 8 + j * 2 + (lrow >> 3);
                bfr[j] = *(const bf16x8*)&sV[wv][pr * 16 + quad * 8];
            }
        }

        #pragma unroll
        for (int j = 0; j < 4; j++) {
            const floatx4 y = __builtin_amdgcn_mfma_f32_16x16x32_bf16(af, bfr[j], fzero, 0, 0, 0);
            #pragma unroll
            for (int r = 0; r < 4; r++)
                sY[t * 1152 + (quad * 4 + r) * 72 + j * 16 + lrow] = f2b(y[r]);
        }

        if (tt < 3) {
            base += 3072;
            cq0 = nq0; cq1 = nq1; ck0 = nk0; ck1 = nk1; cva = nva; cvb = nvb;
        }
    }

    __syncthreads();

    // write 16 complete Z rows (h*512+sg), each 2KB contiguous
    const int h   = tid >> 4;
    const int pos = tid & 15;
    u16* zrow = Z + (size_t)(nb * 8192 + h * 512 + sg) * 1024;
    #pragma unroll
    for (int it = 0; it < 8; it++) {
        const int c16 = it * 16 + pos;
        const int t = c16 >> 3, dc = c16 & 7;
        const uint4 v = *(const uint4*)&sY[t * 1152 + h * 72 + dc * 8];
        *(uint4*)(zrow + c16 * 8) = v;
    }
}

// ---------------- launch ----------------
extern "C" void kernel_launch(void* const* d_in, const int* in_sizes, int n_in,
                              void* d_out, int out_size, void* d_ws, size_t ws_size,
                              hipStream_t stream)
{
    (void)in_sizes; (void)n_in; (void)out_size;
    const float* x  = (const float*)d_in[0];
    const float* Wq = (const float*)d_in[1];
    const float* Wk = (const float*)d_in[2];
    const float* Wv = (const float*)d_in[3];
    const float* Wo = (const float*)d_in[4];
    const float* bq = (const float*)d_in[5];
    const float* bk = (const float*)d_in[6];
    const float* bv = (const float*)d_in[7];
    const float* bo = (const float*)d_in[8];

    const size_t Mtot = 32768;   // 4 * 8192 tokens
    char* ws = (char*)d_ws;
    u16* Xbf  = (u16*)ws;                                   // 64 MB
    u16* Wqkv = (u16*)(ws + (64ull << 20));                 // 6 MB
    u16* Wob  = (u16*)(ws + (64ull << 20) + (6ull << 20));  // 2 MB
    char* dyn = ws + (72ull << 20);
    const size_t fixed = (72ull << 20);

    int c = 4;
    for (int cc = 1; cc <= 4; cc <<= 1) {
        size_t Rr = Mtot / cc;
        if (fixed + Rr * 3072 * 2 + Rr * 1024 * 2 <= ws_size) { c = cc; break; }
    }
    const size_t R = Mtot / c;
    u16* QKV = (u16*)dyn;
    u16* Zb  = (u16*)(dyn + R * 3072 * 2);

    cast_x<<<dim3(4096), dim3(256), 0, stream>>>(x, Xbf, (int)(Mtot * 1024 / 4));
    cast_w<<<dim3(1024), dim3(256), 0, stream>>>(Wq, Wk, Wv, Wo, Wqkv, Wob);

    const int mt  = (int)(R >> 8);          // 256-row tiles; power of 2
    const int msh = __builtin_ctz((unsigned)mt);

    for (int ci = 0; ci < c; ci++) {
        const u16* Ab   = Xbf + (size_t)ci * R * 1024;
        float*     outp = (float*)d_out + (size_t)ci * R * 1024;
        gemm8<true><<<dim3(mt * 12), dim3(512), 0, stream>>>(Ab, Wqkv, bq, bk, bv, QKV, 3072, msh);
        attn_v3<<<dim3((unsigned)(R / 16)), dim3(256), 0, stream>>>(QKV, Zb);
        gemm8<false><<<dim3(mt * 4), dim3(512), 0, stream>>>(Zb, Wob, bo, bo, bo, outp, 1024, msh);
    }
}

// Round 4
// 568.912 us; speedup vs baseline: 1.0876x; 1.0063x over previous
//
#include <hip/hip_runtime.h>
#include <cstdint>
#include <cstddef>

typedef unsigned short u16;
typedef __attribute__((ext_vector_type(8))) __bf16 bf16x8;
typedef __attribute__((ext_vector_type(4))) float floatx4;

typedef const __attribute__((address_space(1))) void* gptr_t;
typedef __attribute__((address_space(3))) void* lptr_t;

__device__ __forceinline__ u16 f2b(float f) {
    unsigned u = __builtin_bit_cast(unsigned, f);
    u += 0x7fffu + ((u >> 16) & 1u);   // RNE; inputs are finite
    return (u16)(u >> 16);
}

// DPP row (16-lane) rotate-reductions — VALU pipe, no DS traffic.
template <int N>
__device__ __forceinline__ float ror_add(float x) {
    int y = __builtin_amdgcn_update_dpp(0, __builtin_bit_cast(int, x), 0x120 + N, 0xF, 0xF, true);
    return x + __builtin_bit_cast(float, y);
}
template <int N>
__device__ __forceinline__ float ror_max(float x) {
    int y = __builtin_amdgcn_update_dpp(0, __builtin_bit_cast(int, x), 0x120 + N, 0xF, 0xF, true);
    return fmaxf(x, __builtin_bit_cast(float, y));
}

// ---------------- fp32 -> bf16 casts ----------------
__global__ void cast_x(const float* __restrict__ in, u16* __restrict__ out, int n4) {
    const int stride = gridDim.x * blockDim.x;
    for (int i = blockIdx.x * blockDim.x + threadIdx.x; i < n4; i += stride) {
        const float4 v = ((const float4*)in)[i];
        ushort4 o;
        o.x = f2b(v.x); o.y = f2b(v.y); o.z = f2b(v.z); o.w = f2b(v.w);
        ((ushort4*)out)[i] = o;
    }
}

__global__ void cast_w(const float* __restrict__ Wq, const float* __restrict__ Wk,
                       const float* __restrict__ Wv, const float* __restrict__ Wo,
                       u16* __restrict__ Wqkv, u16* __restrict__ Wob) {
    const int stride = gridDim.x * blockDim.x;
    for (int i = blockIdx.x * blockDim.x + threadIdx.x; i < 1048576; i += stride) {
        const int which = i >> 18;          // 262144 float4 per matrix
        const int local = i & 0x3FFFF;
        const float* src = which == 0 ? Wq : which == 1 ? Wk : which == 2 ? Wv : Wo;
        const float4 v = ((const float4*)src)[local];
        ushort4 o;
        o.x = f2b(v.x); o.y = f2b(v.y); o.z = f2b(v.z); o.w = f2b(v.w);
        ushort4* dst = which < 3 ? (ushort4*)Wqkv + which * 262144 + local
                                 : (ushort4*)Wob + local;
        *dst = o;
    }
}

// ---------------- 256x256xBK64 8-phase bf16 GEMM, C = A @ B^T + bias ----------------
// (Round-1 verified structure: ~219 us, MfmaUtil ~41%, zero bank conflicts, no spill.
//  Body unchanged; split into two named __global__ wrappers for rocprof visibility.)
// K fixed at 1024 (16 K-tiles -> 8 iterations of 2 tiles).
// 8 waves (2m x 4n), per-wave 128x64 output = acc[8][4] 16x16 fragments.
// LDS 128 KiB: st_16x32 XOR swizzle on BOTH pre-swizzled global source (gload_lds
// writes linearly) and the ds_read address.
// Per phase: {ds_reads, stage 1 half-tile (2 x gload_lds), barrier, lgkmcnt(0),
// setprio(1), 16 MFMA, setprio(0), barrier}; counted vmcnt(4) at phases 3 and 7.

#define MFMA16(va, vb, vc) __builtin_amdgcn_mfma_f32_16x16x32_bf16((va), (vb), (vc), 0, 0, 0)
#define PH_BAR()  __builtin_amdgcn_s_barrier()
#define PH_LGKM() asm volatile("s_waitcnt lgkmcnt(0)" ::: "memory")

template <bool OUT_BF16>
__device__ __forceinline__
void gemm8_body(const u16* __restrict__ A, const u16* __restrict__ B,
                const float* __restrict__ b0, const float* __restrict__ b1,
                const float* __restrict__ b2, void* __restrict__ Cout,
                int N, int mshift)
{
    __shared__ __align__(16) u16 lds[65536];   // 128 KiB

    // XCD-aware bijective swizzle (nwg % 8 == 0 always here), m-major within n
    const int nwg = gridDim.x;
    const int bid = blockIdx.x;
    const int swz = (bid & 7) * (nwg >> 3) + (bid >> 3);
    const int ntile = swz >> mshift;
    const int mtile = swz & ((1 << mshift) - 1);
    const int bm0 = mtile << 8;
    const int bn0 = ntile << 8;

    const int tid  = threadIdx.x;
    const int lane = tid & 63;
    const int wv   = tid >> 6;      // 0..7
    const int wm   = wv >> 2;       // 0..1
    const int wn   = wv & 3;        // 0..3
    const int lrow = lane & 15;
    const int quad = lane >> 4;

    // ---- staging addressing (pre-swizzled global source, linear LDS dst) ----
    const int srow = lane >> 2;                                   // 0..15 within subtile
    const int scol = ((lane & 3) * 8) ^ (((lane >> 5) & 1) << 4); // inverse == forward XOR
    const u16* aS = A + (size_t)(bm0 + wv * 16 + srow) * 1024 + scol;
    const u16* bS = B + (size_t)(bn0 + wv * 16 + srow) * 1024 + scol;
    u16* aD = lds +         wv * 1024 + lane * 8;   // + buf*16384 + half*8192 (+512 for kb=1)
    u16* bD = lds + 32768 + wv * 1024 + lane * 8;

    // ---- fragment read addressing (swizzled) ----
    const int laneSw = lrow * 32 + ((quad * 8) ^ ((lrow >> 3) << 4));
    const u16* pA = lds +         wm * 8192 + laneSw;   // + buf*16384 + i*1024 + kb*512
    const u16* pB = lds + 32768 + wn * 4096 + laneSw;   // + buf*16384 + t*1024 + kb*512

    auto stage = [&](const u16* src, u16* dst, int kt, int half, int buf) {
        const u16* s = src + (size_t)half * 131072 + kt * 64;
        u16* d = dst + buf * 16384 + half * 8192;
        __builtin_amdgcn_global_load_lds((gptr_t)s,        (lptr_t)d,         16, 0, 0);
        __builtin_amdgcn_global_load_lds((gptr_t)(s + 32), (lptr_t)(d + 512), 16, 0, 0);
    };

    // ---- prologue: K0 fully (buf0) + K1.B halves (buf1); retire K0, keep K1.B in flight
    stage(aS, aD, 0, 0, 0);
    stage(aS, aD, 0, 1, 0);
    stage(bS, bD, 0, 0, 0);
    stage(bS, bD, 0, 1, 0);
    asm volatile("" ::: "memory");      // pin issue order: K0 group before K1 group
    stage(bS, bD, 1, 0, 1);
    stage(bS, bD, 1, 1, 1);
    asm volatile("s_waitcnt vmcnt(4)" ::: "memory");
    PH_BAR();

    const floatx4 fz = {0.f, 0.f, 0.f, 0.f};
    floatx4 acc[8][4];
    #pragma unroll
    for (int i = 0; i < 8; ++i)
        #pragma unroll
        for (int t = 0; t < 4; ++t) acc[i][t] = fz;

    bf16x8 a[4][2], p0[2][2], p1[2][2];

    for (int j = 0; j < 8; ++j) {
        const int kt1 = 2 * j + 1;
        const int kt2 = 2 * j + 2;
        const int kt3 = 2 * j + 3;
        const bool more = (j < 7);

        // ===== phase 0: buf0 reads A(m0-3)+B(n0-1) [12]; mfma acc[0-3][0-1]
        #pragma unroll
        for (int i = 0; i < 4; ++i) {
            a[i][0] = *(const bf16x8*)(pA + i * 1024);
            a[i][1] = *(const bf16x8*)(pA + i * 1024 + 512);
        }
        #pragma unroll
        for (int t = 0; t < 2; ++t) {
            p0[t][0] = *(const bf16x8*)(pB + t * 1024);
            p0[t][1] = *(const bf16x8*)(pB + t * 1024 + 512);
        }
        stage(aS, aD, kt1, 0, 1);
        PH_BAR(); PH_LGKM();
        __builtin_amdgcn_s_setprio(1);
        #pragma unroll
        for (int i = 0; i < 4; ++i)
            #pragma unroll
            for (int t = 0; t < 2; ++t) {
                acc[i][t] = MFMA16(a[i][0], p0[t][0], acc[i][t]);
                acc[i][t] = MFMA16(a[i][1], p0[t][1], acc[i][t]);
            }
        __builtin_amdgcn_s_setprio(0);
        PH_BAR();

        // ===== phase 1: buf0 reads B(n2-3) [4]; mfma acc[0-3][2-3]
        #pragma unroll
        for (int t = 0; t < 2; ++t) {
            p1[t][0] = *(const bf16x8*)(pB + 2048 + t * 1024);
            p1[t][1] = *(const bf16x8*)(pB + 2048 + t * 1024 + 512);
        }
        stage(aS, aD, kt1, 1, 1);
        PH_BAR(); PH_LGKM();
        __builtin_amdgcn_s_setprio(1);
        #pragma unroll
        for (int i = 0; i < 4; ++i)
            #pragma unroll
            for (int t = 0; t < 2; ++t) {
                acc[i][2 + t] = MFMA16(a[i][0], p1[t][0], acc[i][2 + t]);
                acc[i][2 + t] = MFMA16(a[i][1], p1[t][1], acc[i][2 + t]);
            }
        __builtin_amdgcn_s_setprio(0);
        PH_BAR();

        // ===== phase 2: buf0 reads A(m4-7) [8]; mfma acc[4-7][2-3]
        #pragma unroll
        for (int i = 0; i < 4; ++i) {
            a[i][0] = *(const bf16x8*)(pA + 4096 + i * 1024);
            a[i][1] = *(const bf16x8*)(pA + 4096 + i * 1024 + 512);
        }
        if (more) stage(bS, bD, kt2, 0, 0);
        PH_BAR(); PH_LGKM();
        __builtin_amdgcn_s_setprio(1);
        #pragma unroll
        for (int i = 0; i < 4; ++i)
            #pragma unroll
            for (int t = 0; t < 2; ++t) {
                acc[4 + i][2 + t] = MFMA16(a[i][0], p1[t][0], acc[4 + i][2 + t]);
                acc[4 + i][2 + t] = MFMA16(a[i][1], p1[t][1], acc[4 + i][2 + t]);
            }
        __builtin_amdgcn_s_setprio(0);
        PH_BAR();

        // ===== phase 3: no reads; mfma acc[4-7][0-1]; counted vmcnt protects phase-4 reads
        if (more) stage(bS, bD, kt2, 1, 0);
        PH_BAR();
        __builtin_amdgcn_s_setprio(1);
        #pragma unroll
        for (int i = 0; i < 4; ++i)
            #pragma unroll
            for (int t = 0; t < 2; ++t) {
                acc[4 + i][t] = MFMA16(a[i][0], p0[t][0], acc[4 + i][t]);
                acc[4 + i][t] = MFMA16(a[i][1], p0[t][1], acc[4 + i][t]);
            }
        __builtin_amdgcn_s_setprio(0);
        if (more) asm volatile("s_waitcnt vmcnt(4)" ::: "memory");
        else      asm volatile("s_waitcnt vmcnt(0)" ::: "memory");
        PH_BAR();

        // ===== phase 4: buf1 reads A(m0-3)+B(n0-1); mfma acc[0-3][0-1]
        #pragma unroll
        for (int i = 0; i < 4; ++i) {
            a[i][0] = *(const bf16x8*)(pA + 16384 + i * 1024);
            a[i][1] = *(const bf16x8*)(pA + 16384 + i * 1024 + 512);
        }
        #pragma unroll
        for (int t = 0; t < 2; ++t) {
            p0[t][0] = *(const bf16x8*)(pB + 16384 + t * 1024);
            p0[t][1] = *(const bf16x8*)(pB + 16384 + t * 1024 + 512);
        }
        if (more) stage(aS, aD, kt2, 0, 0);
        PH_BAR(); PH_LGKM();
        __builtin_amdgcn_s_setprio(1);
        #pragma unroll
        for (int i = 0; i < 4; ++i)
            #pragma unroll
            for (int t = 0; t < 2; ++t) {
                acc[i][t] = MFMA16(a[i][0], p0[t][0], acc[i][t]);
                acc[i][t] = MFMA16(a[i][1], p0[t][1], acc[i][t]);
            }
        __builtin_amdgcn_s_setprio(0);
        PH_BAR();

        // ===== phase 5: buf1 reads B(n2-3); mfma acc[0-3][2-3]
        #pragma unroll
        for (int t = 0; t < 2; ++t) {
            p1[t][0] = *(const bf16x8*)(pB + 16384 + 2048 + t * 1024);
            p1[t][1] = *(const bf16x8*)(pB + 16384 + 2048 + t * 1024 + 512);
        }
        if (more) stage(aS, aD, kt2, 1, 0);
        PH_BAR(); PH_LGKM();
        __builtin_amdgcn_s_setprio(1);
        #pragma unroll
        for (int i = 0; i < 4; ++i)
            #pragma unroll
            for (int t = 0; t < 2; ++t) {
                acc[i][2 + t] = MFMA16(a[i][0], p1[t][0], acc[i][2 + t]);
                acc[i][2 + t] = MFMA16(a[i][1], p1[t][1], acc[i][2 + t]);
            }
        __builtin_amdgcn_s_setprio(0);
        PH_BAR();

        // ===== phase 6: buf1 reads A(m4-7); mfma acc[4-7][2-3]
        #pragma unroll
        for (int i = 0; i < 4; ++i) {
            a[i][0] = *(const bf16x8*)(pA + 16384 + 4096 + i * 1024);
            a[i][1] = *(const bf16x8*)(pA + 16384 + 4096 + i * 1024 + 512);
        }
        if (more) stage(bS, bD, kt3, 0, 1);
        PH_BAR(); PH_LGKM();
        __builtin_amdgcn_s_setprio(1);
        #pragma unroll
        for (int i = 0; i < 4; ++i)
            #pragma unroll
            for (int t = 0; t < 2; ++t) {
                acc[4 + i][2 + t] = MFMA16(a[i][0], p1[t][0], acc[4 + i][2 + t]);
                acc[4 + i][2 + t] = MFMA16(a[i][1], p1[t][1], acc[4 + i][2 + t]);
            }
        __builtin_amdgcn_s_setprio(0);
        PH_BAR();

        // ===== phase 7: no reads; mfma acc[4-7][0-1]; counted vmcnt protects next ph0
        if (more) stage(bS, bD, kt3, 1, 1);
        PH_BAR();
        __builtin_amdgcn_s_setprio(1);
        #pragma unroll
        for (int i = 0; i < 4; ++i)
            #pragma unroll
            for (int t = 0; t < 2; ++t) {
                acc[4 + i][t] = MFMA16(a[i][0], p0[t][0], acc[4 + i][t]);
                acc[4 + i][t] = MFMA16(a[i][1], p0[t][1], acc[4 + i][t]);
            }
        __builtin_amdgcn_s_setprio(0);
        asm volatile("s_waitcnt vmcnt(4)" ::: "memory");
        PH_BAR();
    }

    // ---- epilogue: bias + store ----
    float bsv[4];
    #pragma unroll
    for (int t = 0; t < 4; ++t) {
        const int n = bn0 + wn * 64 + t * 16 + lrow;
        const float* bp = n < 1024 ? b0 : (n < 2048 ? b1 : b2);
        bsv[t] = bp[n & 1023];
    }
    #pragma unroll
    for (int i = 0; i < 8; ++i) {
        const int mbase = bm0 + wm * 128 + i * 16 + quad * 4;
        #pragma unroll
        for (int t = 0; t < 4; ++t) {
            const int n = bn0 + wn * 64 + t * 16 + lrow;
            #pragma unroll
            for (int r = 0; r < 4; ++r) {
                const float v = acc[i][t][r] + bsv[t];
                const size_t idx = (size_t)(mbase + r) * N + n;
                if constexpr (OUT_BF16) ((u16*)Cout)[idx] = f2b(v);
                else                    ((float*)Cout)[idx] = v;
            }
        }
    }
}

__global__ __launch_bounds__(512, 2)
void gemm_qkv(const u16* __restrict__ A, const u16* __restrict__ B,
              const float* __restrict__ b0, const float* __restrict__ b1,
              const float* __restrict__ b2, u16* __restrict__ C, int N, int mshift)
{ gemm8_body<true>(A, B, b0, b1, b2, (void*)C, N, mshift); }

__global__ __launch_bounds__(512, 2)
void gemm_out(const u16* __restrict__ A, const u16* __restrict__ B,
              const float* __restrict__ b0, float* __restrict__ C, int N, int mshift)
{ gemm8_body<false>(A, B, b0, b0, b0, (void*)C, N, mshift); }

// ---------------- attention v5: DPP softmax, direct Z stores, no sY/barrier -------
// vs v4: PV output registers map directly to Z columns (column = j*16+lrow == the
// physical d of y[r] — same identity the old sY path relied on), so store Z
// straight from the MFMA result as u16 stores (32B chunks; each Z row fully
// covered by one block -> L2 assembles full lines, no HBM write amplification).
// Removes: 36KB sY LDS (50KB->13KB, 3->4 blocks/CU), block barrier, ~96 DS ops
// per wave. Keeps: per-wave V^T transpose in LDS, DPP softmax, token prefetch.
__global__ __launch_bounds__(256, 4)
void attn_v5(const u16* __restrict__ QKV, u16* __restrict__ Z)
{
    __shared__ __align__(16) u16 sV[4][1024];     // per-wave V^T, phys_row=(d&7)*8+(d>>3)
    __shared__ __align__(16) u16 sA[4][640];      // per-wave A, rows of 40 (k=16..31 zeroed)

    const int tid  = threadIdx.x;
    const int lane = tid & 63;
    const int wv   = tid >> 6;
    const int lrow = lane & 15;
    const int quad = lane >> 4;
    const int pp   = lane >> 3;   // l-pair 0..7
    const int cc   = lane & 7;    // d-chunk 0..7

    #pragma unroll
    for (int i = 0; i < 4; i++) {
        const int idx = i * 64 + lane;
        sA[wv][(idx >> 4) * 40 + 16 + (idx & 15)] = 0;
    }

    const int tgrp = blockIdx.x * 16;
    const int nb   = tgrp >> 13;
    const int sg   = (tgrp & 8191) >> 4;

    const floatx4 fzero = {0.f, 0.f, 0.f, 0.f};

    const u16* base  = QKV + (size_t)(tgrp + wv * 4) * 3072;
    u16*       zbase = Z + (size_t)(nb * 8192 + sg) * 1024;  // + h*524288 + t*64 + col

    // preload token 0
    bf16x8 cq0 = *(const bf16x8*)(base + lrow * 64      + quad * 8);
    bf16x8 cq1 = *(const bf16x8*)(base + lrow * 64 + 32 + quad * 8);
    bf16x8 ck0 = *(const bf16x8*)(base + 1024 + lrow * 64      + quad * 8);
    bf16x8 ck1 = *(const bf16x8*)(base + 1024 + lrow * 64 + 32 + quad * 8);
    bf16x8 cva = *(const bf16x8*)(base + 2048 + (2 * pp)     * 64 + cc * 8);
    bf16x8 cvb = *(const bf16x8*)(base + 2048 + (2 * pp + 1) * 64 + cc * 8);

    #pragma unroll
    for (int tt = 0; tt < 4; tt++) {
        const int t = wv * 4 + tt;

        // prefetch token tt+1 (in flight across this token's compute)
        bf16x8 nq0, nq1, nk0, nk1, nva, nvb;
        if (tt < 3) {
            const u16* nbase = base + 3072;
            nq0 = *(const bf16x8*)(nbase + lrow * 64      + quad * 8);
            nq1 = *(const bf16x8*)(nbase + lrow * 64 + 32 + quad * 8);
            nk0 = *(const bf16x8*)(nbase + 1024 + lrow * 64      + quad * 8);
            nk1 = *(const bf16x8*)(nbase + 1024 + lrow * 64 + 32 + quad * 8);
            nva = *(const bf16x8*)(nbase + 2048 + (2 * pp)     * 64 + cc * 8);
            nvb = *(const bf16x8*)(nbase + 2048 + (2 * pp + 1) * 64 + cc * 8);
        }

        // V transpose into per-wave LDS (conflict-free b32 writes)
        #pragma unroll
        for (int s = 0; s < 8; s++) {
            const unsigned pv = (unsigned)__builtin_bit_cast(u16, (__bf16)cva[s]) |
                                ((unsigned)__builtin_bit_cast(u16, (__bf16)cvb[s]) << 16);
            *(unsigned*)&sV[wv][(s * 8 + cc) * 16 + 2 * pp] = pv;
        }

        floatx4 e = fzero;
        e = __builtin_amdgcn_mfma_f32_16x16x32_bf16(cq0, ck0, e, 0, 0, 0);
        e = __builtin_amdgcn_mfma_f32_16x16x32_bf16(cq1, ck1, e, 0, 0, 0);

        // softmax over l (= the 16 lanes of this quad's DPP row), pure VALU
        #pragma unroll
        for (int r = 0; r < 4; r++) {
            const float xv = e[r] * 0.03125f;    // 1/sqrt(1024)
            float mx = xv;
            mx = ror_max<1>(mx); mx = ror_max<2>(mx);
            mx = ror_max<4>(mx); mx = ror_max<8>(mx);
            const float p = __expf(xv - mx);
            float s = p;
            s = ror_add<1>(s); s = ror_add<2>(s);
            s = ror_add<4>(s); s = ror_add<8>(s);
            sA[wv][(quad * 4 + r) * 40 + lrow] = f2b(p * __builtin_amdgcn_rcpf(s));
        }

        const bf16x8 af = *(const bf16x8*)&sA[wv][lrow * 40 + quad * 8];

        bf16x8 bfr[4];
        #pragma unroll
        for (int j = 0; j < 4; j++)
            #pragma unroll
            for (int jj = 0; jj < 8; jj++)
                bfr[j][jj] = __builtin_bit_cast(__bf16, (u16)0);
        if (quad < 2) {
            #pragma unroll
            for (int j = 0; j < 4; j++) {
                const int pr = (lrow & 7) * 8 + j * 2 + (lrow >> 3);
                bfr[j] = *(const bf16x8*)&sV[wv][pr * 16 + quad * 8];
            }
        }

        // PV + direct Z store: Z row = h*512+sg (h = quad*4+r), col = t*64+j*16+lrow
        #pragma unroll
        for (int j = 0; j < 4; j++) {
            const floatx4 y = __builtin_amdgcn_mfma_f32_16x16x32_bf16(af, bfr[j], fzero, 0, 0, 0);
            #pragma unroll
            for (int r = 0; r < 4; r++)
                zbase[(size_t)(quad * 4 + r) * 524288 + t * 64 + j * 16 + lrow] = f2b(y[r]);
        }

        if (tt < 3) {
            base += 3072;
            cq0 = nq0; cq1 = nq1; ck0 = nk0; ck1 = nk1; cva = nva; cvb = nvb;
        }
    }
}

// ---------------- launch ----------------
extern "C" void kernel_launch(void* const* d_in, const int* in_sizes, int n_in,
                              void* d_out, int out_size, void* d_ws, size_t ws_size,
                              hipStream_t stream)
{
    (void)in_sizes; (void)n_in; (void)out_size;
    const float* x  = (const float*)d_in[0];
    const float* Wq = (const float*)d_in[1];
    const float* Wk = (const float*)d_in[2];
    const float* Wv = (const float*)d_in[3];
    const float* Wo = (const float*)d_in[4];
    const float* bq = (const float*)d_in[5];
    const float* bk = (const float*)d_in[6];
    const float* bv = (const float*)d_in[7];
    const float* bo = (const float*)d_in[8];

    const size_t Mtot = 32768;   // 4 * 8192 tokens
    char* ws = (char*)d_ws;
    u16* Xbf  = (u16*)ws;                                   // 64 MB
    u16* Wqkv = (u16*)(ws + (64ull << 20));                 // 6 MB
    u16* Wob  = (u16*)(ws + (64ull << 20) + (6ull << 20));  // 2 MB
    char* dyn = ws + (72ull << 20);
    const size_t fixed = (72ull << 20);

    int c = 4;
    for (int cc = 1; cc <= 4; cc <<= 1) {
        size_t Rr = Mtot / cc;
        if (fixed + Rr * 3072 * 2 + Rr * 1024 * 2 <= ws_size) { c = cc; break; }
    }
    const size_t R = Mtot / c;
    u16* QKV = (u16*)dyn;
    u16* Zb  = (u16*)(dyn + R * 3072 * 2);

    cast_x<<<dim3(4096), dim3(256), 0, stream>>>(x, Xbf, (int)(Mtot * 1024 / 4));
    cast_w<<<dim3(1024), dim3(256), 0, stream>>>(Wq, Wk, Wv, Wo, Wqkv, Wob);

    const int mt  = (int)(R >> 8);          // 256-row tiles; power of 2
    const int msh = __builtin_ctz((unsigned)mt);

    for (int ci = 0; ci < c; ci++) {
        const u16* Ab   = Xbf + (size_t)ci * R * 1024;
        float*     outp = (float*)d_out + (size_t)ci * R * 1024;
        gemm_qkv<<<dim3(mt * 12), dim3(512), 0, stream>>>(Ab, Wqkv, bq, bk, bv, QKV, 3072, msh);
        attn_v5<<<dim3((unsigned)(R / 16)), dim3(256), 0, stream>>>(QKV, Zb);
        gemm_out<<<dim3(mt * 4), dim3(512), 0, stream>>>(Zb, Wob, bo, outp, 1024, msh);
    }
}